// Round 3
// baseline (262.340 us; speedup 1.0000x reference)
//
#include <hip/hip_runtime.h>
#include <math.h>

#define Bn 8
#define Nn 2048
#define FIn 256
#define FOn 128

typedef __attribute__((ext_vector_type(8))) short short8;
typedef __attribute__((ext_vector_type(4))) float f32x4;
typedef __attribute__((ext_vector_type(4))) unsigned short ushort4v;

__device__ __forceinline__ unsigned short f2bf(float x){
    union { float f; unsigned u; } v; v.f = x;
    unsigned r = v.u + 0x7fffu + ((v.u >> 16) & 1u);
    return (unsigned short)(r >> 16);
}

// K0: WT[o][k] = bf16(W[k][o])   (128 x 256)
__global__ void k0_wt(const float* __restrict__ W, unsigned short* __restrict__ WT){
    int o = blockIdx.x, k = threadIdx.x;
    WT[o*FIn + k] = f2bf(W[k*FOn + o]);
}

// K1: Wh = h @ W via bf16 MFMA; emits WhT (bf16, transposed) + s1/s2.
// 32 rows/block, grid 512 (2 blocks/CU). 4 waves = 2 row-groups x 2 col-halves.
__global__ __launch_bounds__(256) void k1_gemm(const float* __restrict__ h,
        const unsigned short* __restrict__ WT, const float* __restrict__ a,
        unsigned short* __restrict__ WhT, float* __restrict__ s1, float* __restrict__ s2){
    __shared__ __align__(16) unsigned short tr[128][48];   // 32 i-cols + pad (96B row stride, 16B-aligned)
    __shared__ float ps1[2][32], ps2[2][32];
    int t = threadIdx.x, lane = t & 63, w = t >> 6;
    int rg = w >> 1, ch = w & 1;
    int l16 = lane & 15, khalf = (lane >> 4) * 8;
    long g0 = (long)blockIdx.x * 32;
    int b = (int)(g0 >> 11);
    int i0 = (int)(g0 & 2047);
    long row = g0 + rg*16 + l16;
    f32x4 acc[4];
    #pragma unroll
    for (int nf=0;nf<4;nf++) acc[nf] = (f32x4){0.f,0.f,0.f,0.f};
    #pragma unroll
    for (int ks=0; ks<8; ks++){
        int kb = ks*32 + khalf;
        const float4* hp = (const float4*)(h + row*FIn + kb);
        float4 h0 = hp[0], h1 = hp[1];
        short8 af;
        af[0]=(short)f2bf(h0.x); af[1]=(short)f2bf(h0.y); af[2]=(short)f2bf(h0.z); af[3]=(short)f2bf(h0.w);
        af[4]=(short)f2bf(h1.x); af[5]=(short)f2bf(h1.y); af[6]=(short)f2bf(h1.z); af[7]=(short)f2bf(h1.w);
        #pragma unroll
        for (int nf=0;nf<4;nf++){
            short8 bfv = *(const short8*)(WT + (ch*64 + nf*16 + l16)*FIn + kb);
            acc[nf] = __builtin_amdgcn_mfma_f32_16x16x32_bf16(af, bfv, acc[nf], 0, 0, 0);
        }
    }
    // s1/s2 partials over this col-half; reduce across the 16 col-lanes
    {
        float a1v[4], a2v[4];
        #pragma unroll
        for (int nf=0;nf<4;nf++){
            a1v[nf] = a[ch*64 + nf*16 + l16];
            a2v[nf] = a[FOn + ch*64 + nf*16 + l16];
        }
        #pragma unroll
        for (int r=0;r<4;r++){
            float u1 = 0.f, u2 = 0.f;
            #pragma unroll
            for (int nf=0;nf<4;nf++){ u1 = fmaf(acc[nf][r], a1v[nf], u1); u2 = fmaf(acc[nf][r], a2v[nf], u2); }
            u1 += __shfl_xor(u1, 1); u1 += __shfl_xor(u1, 2); u1 += __shfl_xor(u1, 4); u1 += __shfl_xor(u1, 8);
            u2 += __shfl_xor(u2, 1); u2 += __shfl_xor(u2, 2); u2 += __shfl_xor(u2, 4); u2 += __shfl_xor(u2, 8);
            if (l16 == 0){
                int rloc = rg*16 + ((lane>>4)<<2) + r;
                ps1[ch][rloc] = u1; ps2[ch][rloc] = u2;
            }
        }
    }
    // transpose to LDS (bf16)
    int rbase = rg*16 + ((lane>>4)<<2);
    #pragma unroll
    for (int nf=0;nf<4;nf++)
        #pragma unroll
        for (int r=0;r<4;r++)
            tr[ch*64 + nf*16 + l16][rbase + r] = f2bf(acc[nf][r]);
    __syncthreads();
    if (t < 32){
        s1[g0 + t] = ps1[0][t] + ps1[1][t];
        s2[g0 + t] = ps2[0][t] + ps2[1][t];
    }
    int o = t >> 1, seg = t & 1;
    short8 v0 = *(const short8*)&tr[o][seg*16];
    short8 v1 = *(const short8*)&tr[o][seg*16 + 8];
    unsigned short* dst = WhT + ((long)(b*FOn + o))*Nn + i0 + seg*16;
    *(short8*)(dst)     = v0;
    *(short8*)(dst + 8) = v1;
}

// K3: fused masked-softmax attention. Block = (b, 32-row i-tile), 512 threads = 8 waves.
// Single j-stream of 32 tiles x 64. Scores on VALU (16-lane shfl reduce), online softmax,
// P(bf16, LDS parity double-buffer) @ WhT (B-frags DIRECT from global/L2 - no LDS staging).
// One barrier per tile. adj: depth-2 named-register prefetch. XCD swizzle: b = bid&7.
__global__ __launch_bounds__(512) void k3_flash(const int* __restrict__ adj,
        const unsigned short* __restrict__ WhT, const float* __restrict__ s1g,
        const float* __restrict__ s2g, float* __restrict__ out){
    __shared__ __align__(16) unsigned short pt[2][32][72];
    __shared__ float m_s[32], l_s[32], rs_s[2][32];
    int t = threadIdx.x, lane = t & 63, w = t >> 6;
    int bid = blockIdx.x;
    int b = bid & 7;                 // XCD = bid%8 = b: per-b WhT slice stays in one L2
    int i0 = (bid >> 3) * 32;
    int q = t >> 4;                  // 0..31: row
    int c = t & 15;                  // 4 j-cols per thread
    int rg = w >> 2, cq = w & 3;     // MFMA wave tile: rows rg*16.., cols cq*32..
    int l16 = lane & 15, khalf = (lane >> 4) * 8;
    if (t < 32){ m_s[t] = -INFINITY; l_s[t] = 0.f; }
    f32x4 acc[2];
    acc[0] = (f32x4){0.f,0.f,0.f,0.f};
    acc[1] = (f32x4){0.f,0.f,0.f,0.f};
    float s1r = s1g[b*Nn + i0 + q];
    const int* ajbase = adj + ((long)(b*Nn + i0 + q))*Nn + c*4;
    const float* s2base = s2g + b*Nn + c*4;
    const unsigned short* Bbase = WhT + ((long)(b*FOn + cq*32 + l16))*Nn + khalf;
    int4 ajA = *(const int4*)(ajbase + 0*64);
    int4 ajB = *(const int4*)(ajbase + 1*64);
    __syncthreads();

#define SCORE_TILE(AJREG, PAR, J0)                                              \
    {                                                                           \
        int4 av = AJREG;                                                        \
        int jn2 = (J0) + 128;  jn2 = jn2 < Nn ? jn2 : Nn - 64;                  \
        AJREG = *(const int4*)(ajbase + jn2);                                   \
        float4 s2c = *(const float4*)(s2base + (J0));                           \
        float sc0 = s1r + s2c.x; sc0 = sc0 > 0.f ? sc0 : 0.2f*sc0; sc0 = av.x > 0 ? sc0 : -9e15f; \
        float sc1 = s1r + s2c.y; sc1 = sc1 > 0.f ? sc1 : 0.2f*sc1; sc1 = av.y > 0 ? sc1 : -9e15f; \
        float sc2 = s1r + s2c.z; sc2 = sc2 > 0.f ? sc2 : 0.2f*sc2; sc2 = av.z > 0 ? sc2 : -9e15f; \
        float sc3 = s1r + s2c.w; sc3 = sc3 > 0.f ? sc3 : 0.2f*sc3; sc3 = av.w > 0 ? sc3 : -9e15f; \
        float tm = fmaxf(fmaxf(sc0, sc1), fmaxf(sc2, sc3));                     \
        tm = fmaxf(tm, __shfl_xor(tm, 1));                                      \
        tm = fmaxf(tm, __shfl_xor(tm, 2));                                      \
        tm = fmaxf(tm, __shfl_xor(tm, 4));                                      \
        tm = fmaxf(tm, __shfl_xor(tm, 8));                                      \
        float mo = m_s[q];                                                      \
        float mn = fmaxf(mo, tm);                                               \
        float rsc = __expf(mo - mn);                                            \
        float p0 = __expf(sc0 - mn), p1 = __expf(sc1 - mn);                     \
        float p2 = __expf(sc2 - mn), p3 = __expf(sc3 - mn);                     \
        float ps = (p0+p1)+(p2+p3);                                             \
        ps += __shfl_xor(ps, 1); ps += __shfl_xor(ps, 2);                       \
        ps += __shfl_xor(ps, 4); ps += __shfl_xor(ps, 8);                       \
        if (c == 0){ m_s[q] = mn; l_s[q] = l_s[q]*rsc + ps; rs_s[PAR][q] = rsc; } \
        ushort4v pv;                                                            \
        pv[0] = f2bf(p0); pv[1] = f2bf(p1); pv[2] = f2bf(p2); pv[3] = f2bf(p3); \
        *(ushort4v*)&pt[PAR][q][c*4] = pv;                                      \
    }

#define MFMA_TILE(PAR, J0)                                                      \
    {                                                                           \
        __syncthreads();                                                        \
        float rv0 = rs_s[PAR][rg*16 + ((lane>>4)<<2) + 0];                      \
        float rv1 = rs_s[PAR][rg*16 + ((lane>>4)<<2) + 1];                      \
        float rv2 = rs_s[PAR][rg*16 + ((lane>>4)<<2) + 2];                      \
        float rv3 = rs_s[PAR][rg*16 + ((lane>>4)<<2) + 3];                      \
        acc[0][0]*=rv0; acc[0][1]*=rv1; acc[0][2]*=rv2; acc[0][3]*=rv3;         \
        acc[1][0]*=rv0; acc[1][1]*=rv1; acc[1][2]*=rv2; acc[1][3]*=rv3;         \
        const unsigned short* Bp = Bbase + (J0);                                \
        _Pragma("unroll")                                                       \
        for (int kk=0;kk<2;kk++){                                               \
            short8 af = *(const short8*)&pt[PAR][rg*16 + l16][kk*32 + khalf];   \
            short8 b0 = *(const short8*)(Bp + kk*32);                           \
            short8 b1 = *(const short8*)(Bp + 16*Nn + kk*32);                   \
            acc[0] = __builtin_amdgcn_mfma_f32_16x16x32_bf16(af, b0, acc[0], 0, 0, 0); \
            acc[1] = __builtin_amdgcn_mfma_f32_16x16x32_bf16(af, b1, acc[1], 0, 0, 0); \
        }                                                                       \
    }

    #pragma unroll 1
    for (int pr = 0; pr < 16; pr++){
        int j0 = pr*128;
        SCORE_TILE(ajA, 0, j0)
        MFMA_TILE(0, j0)
        SCORE_TILE(ajB, 1, j0 + 64)
        MFMA_TILE(1, j0 + 64)
    }
#undef SCORE_TILE
#undef MFMA_TILE

    __syncthreads();
    // epilogue: /l, elu, store fp32
    int rb = rg*16 + ((lane>>4)<<2);
    #pragma unroll
    for (int reg=0;reg<4;reg++){
        int r = rb + reg;
        float inv = 1.f / l_s[r];
        #pragma unroll
        for (int nf=0;nf<2;nf++){
            float v = acc[nf][reg] * inv;
            v = v > 0.f ? v : (__expf(v) - 1.f);
            out[((long)(b*Nn + i0 + r))*FOn + cq*32 + nf*16 + l16] = v;
        }
    }
}

extern "C" void kernel_launch(void* const* d_in, const int* in_sizes, int n_in,
                              void* d_out, int out_size, void* d_ws, size_t ws_size,
                              hipStream_t stream){
    const float* h  = (const float*)d_in[0];
    const int* adj  = (const int*)d_in[1];
    const float* W  = (const float*)d_in[2];
    const float* a  = (const float*)d_in[3];
    float* out = (float*)d_out;
    char* ws = (char*)d_ws;
    unsigned short* WT  = (unsigned short*)(ws);                   //    65,536 B (128x256 bf16)
    unsigned short* WhT = (unsigned short*)(ws + 65536);           // 4,194,304 B (8x128x2048 bf16)
    float* s1           = (float*)(ws + 65536 + 4194304);          //    65,536 B
    float* s2           = (float*)(ws + 65536 + 4194304 + 65536);  //    65,536 B

    k0_wt   <<<128, 256, 0, stream>>>(W, WT);
    k1_gemm <<<512, 256, 0, stream>>>(h, WT, a, WhT, s1, s2);
    k3_flash<<<512, 512, 0, stream>>>(adj, WhT, s1, s2, out);
}

// Round 4
// 229.395 us; speedup vs baseline: 1.1436x; 1.1436x over previous
//
#include <hip/hip_runtime.h>
#include <math.h>

#define Bn 8
#define Nn 2048
#define FIn 256
#define FOn 128

typedef __attribute__((ext_vector_type(8))) short short8;
typedef __attribute__((ext_vector_type(4))) float f32x4;
typedef __attribute__((ext_vector_type(4))) unsigned short ushort4v;

__device__ __forceinline__ unsigned short f2bf(float x){
    union { float f; unsigned u; } v; v.f = x;
    unsigned r = v.u + 0x7fffu + ((v.u >> 16) & 1u);
    return (unsigned short)(r >> 16);
}

// K0: WT[o][k] = bf16(W[k][o])   (128 x 256)
__global__ void k0_wt(const float* __restrict__ W, unsigned short* __restrict__ WT){
    int o = blockIdx.x, k = threadIdx.x;
    WT[o*FIn + k] = f2bf(W[k*FOn + o]);
}

// K1: Wh = h @ W via bf16 MFMA; emits WhT (bf16, transposed) + s1/s2.
// 32 rows/block, grid 512 (2 blocks/CU). 4 waves = 2 row-groups x 2 col-halves.
__global__ __launch_bounds__(256) void k1_gemm(const float* __restrict__ h,
        const unsigned short* __restrict__ WT, const float* __restrict__ a,
        unsigned short* __restrict__ WhT, float* __restrict__ s1, float* __restrict__ s2){
    __shared__ __align__(16) unsigned short tr[128][48];
    __shared__ float ps1[2][32], ps2[2][32];
    int t = threadIdx.x, lane = t & 63, w = t >> 6;
    int rg = w >> 1, ch = w & 1;
    int l16 = lane & 15, khalf = (lane >> 4) * 8;
    long g0 = (long)blockIdx.x * 32;
    int b = (int)(g0 >> 11);
    int i0 = (int)(g0 & 2047);
    long row = g0 + rg*16 + l16;
    f32x4 acc[4];
    #pragma unroll
    for (int nf=0;nf<4;nf++) acc[nf] = (f32x4){0.f,0.f,0.f,0.f};
    #pragma unroll
    for (int ks=0; ks<8; ks++){
        int kb = ks*32 + khalf;
        const float4* hp = (const float4*)(h + row*FIn + kb);
        float4 h0 = hp[0], h1 = hp[1];
        short8 af;
        af[0]=(short)f2bf(h0.x); af[1]=(short)f2bf(h0.y); af[2]=(short)f2bf(h0.z); af[3]=(short)f2bf(h0.w);
        af[4]=(short)f2bf(h1.x); af[5]=(short)f2bf(h1.y); af[6]=(short)f2bf(h1.z); af[7]=(short)f2bf(h1.w);
        #pragma unroll
        for (int nf=0;nf<4;nf++){
            short8 bfv = *(const short8*)(WT + (ch*64 + nf*16 + l16)*FIn + kb);
            acc[nf] = __builtin_amdgcn_mfma_f32_16x16x32_bf16(af, bfv, acc[nf], 0, 0, 0);
        }
    }
    {
        float a1v[4], a2v[4];
        #pragma unroll
        for (int nf=0;nf<4;nf++){
            a1v[nf] = a[ch*64 + nf*16 + l16];
            a2v[nf] = a[FOn + ch*64 + nf*16 + l16];
        }
        #pragma unroll
        for (int r=0;r<4;r++){
            float u1 = 0.f, u2 = 0.f;
            #pragma unroll
            for (int nf=0;nf<4;nf++){ u1 = fmaf(acc[nf][r], a1v[nf], u1); u2 = fmaf(acc[nf][r], a2v[nf], u2); }
            u1 += __shfl_xor(u1, 1); u1 += __shfl_xor(u1, 2); u1 += __shfl_xor(u1, 4); u1 += __shfl_xor(u1, 8);
            u2 += __shfl_xor(u2, 1); u2 += __shfl_xor(u2, 2); u2 += __shfl_xor(u2, 4); u2 += __shfl_xor(u2, 8);
            if (l16 == 0){
                int rloc = rg*16 + ((lane>>4)<<2) + r;
                ps1[ch][rloc] = u1; ps2[ch][rloc] = u2;
            }
        }
    }
    int rbase = rg*16 + ((lane>>4)<<2);
    #pragma unroll
    for (int nf=0;nf<4;nf++)
        #pragma unroll
        for (int r=0;r<4;r++)
            tr[ch*64 + nf*16 + l16][rbase + r] = f2bf(acc[nf][r]);
    __syncthreads();
    if (t < 32){
        s1[g0 + t] = ps1[0][t] + ps1[1][t];
        s2[g0 + t] = ps2[0][t] + ps2[1][t];
    }
    int o = t >> 1, seg = t & 1;
    short8 v0 = *(const short8*)&tr[o][seg*16];
    short8 v1 = *(const short8*)&tr[o][seg*16 + 8];
    unsigned short* dst = WhT + ((long)(b*FOn + o))*Nn + i0 + seg*16;
    *(short8*)(dst)     = v0;
    *(short8*)(dst + 8) = v1;
}

// K3: fused masked-softmax attention. Block = (b, 32-row i-tile), 512 threads = 8 waves,
// grid 512 (2 blocks/CU, ~50% occ). Single j-stream, 32 tiles of 64.
// V tile: depth-1 register prefetch -> LDS parity double-buffer (coalesced, 128B lines).
// adj: depth-2 rotating register prefetch (HBM ~900cy). s2: staged once in LDS.
// One barrier per tile. XCD pin: b = bid&7.
__global__ __launch_bounds__(512) void k3_flash(const int* __restrict__ adj,
        const unsigned short* __restrict__ WhT, const float* __restrict__ s1g,
        const float* __restrict__ s2g, float* __restrict__ out){
    __shared__ __align__(16) unsigned short vt[2][128][72];
    __shared__ __align__(16) unsigned short pt[2][32][72];
    __shared__ float s2t[Nn];
    __shared__ float m_s[32], l_s[32], rs_s[2][32];
    int t = threadIdx.x, lane = t & 63, w = t >> 6;
    int bid = blockIdx.x;
    int b = bid & 7;
    int i0 = (bid >> 3) * 32;
    int q = t >> 4;                  // 0..31: score row
    int c = t & 15;                  // 4 j-cols per thread
    int rg = w >> 2, cq = w & 3;     // MFMA wave tile: rows rg*16.., cols cq*32..
    int l16 = lane & 15, khalf = (lane >> 4) * 8;
    if (t < 32){ m_s[t] = -INFINITY; l_s[t] = 0.f; }
    *(float4*)&s2t[t*4] = *(const float4*)(s2g + b*Nn + t*4);
    f32x4 acc[2];
    acc[0] = (f32x4){0.f,0.f,0.f,0.f};
    acc[1] = (f32x4){0.f,0.f,0.f,0.f};
    float s1r = s1g[b*Nn + i0 + q];
    const int* ajbase = adj + ((long)(b*Nn + i0 + q))*Nn + c*4;
    // V-stage: thread covers rows vrow, vrow+64 at j-segment vj (8 bf16 each)
    int vrow = t >> 3, vj = (t & 7) * 8;
    const unsigned short* vp0 = WhT + ((long)(b*FOn + vrow))*Nn + vj;
    const unsigned short* vp1 = vp0 + 64*Nn;
    // prefetch: V tile 0 (depth 1), adj tiles 0,1 (depth 2)
    short8 vA0 = *(const short8*)(vp0);
    short8 vA1 = *(const short8*)(vp1);
    int4 ajA = *(const int4*)(ajbase);
    int4 ajB = *(const int4*)(ajbase + 64);
    __syncthreads();

    #pragma unroll 1
    for (int jt = 0; jt < 32; jt++){
        int j0 = jt*64;
        int par = jt & 1;
        // consume V regs -> LDS, immediately re-issue next tile's V loads
        *(short8*)&vt[par][vrow][vj]      = vA0;
        *(short8*)&vt[par][vrow + 64][vj] = vA1;
        int jn = (jt < 31) ? j0 + 64 : j0;
        vA0 = *(const short8*)(vp0 + jn);
        vA1 = *(const short8*)(vp1 + jn);
        // adj rotating queue: consume A, shift B->A, issue jt+2
        int4 av = ajA; ajA = ajB;
        int jn2 = (jt < 30) ? j0 + 128 : j0;
        ajB = *(const int4*)(ajbase + jn2);
        // scores + online softmax (4 elems/thread, 16 threads per row)
        float4 s2c = *(const float4*)&s2t[j0 + c*4];
        float sc0 = s1r + s2c.x; sc0 = sc0 > 0.f ? sc0 : 0.2f*sc0; sc0 = av.x > 0 ? sc0 : -9e15f;
        float sc1 = s1r + s2c.y; sc1 = sc1 > 0.f ? sc1 : 0.2f*sc1; sc1 = av.y > 0 ? sc1 : -9e15f;
        float sc2 = s1r + s2c.z; sc2 = sc2 > 0.f ? sc2 : 0.2f*sc2; sc2 = av.z > 0 ? sc2 : -9e15f;
        float sc3 = s1r + s2c.w; sc3 = sc3 > 0.f ? sc3 : 0.2f*sc3; sc3 = av.w > 0 ? sc3 : -9e15f;
        float tm = fmaxf(fmaxf(sc0, sc1), fmaxf(sc2, sc3));
        tm = fmaxf(tm, __shfl_xor(tm, 1));
        tm = fmaxf(tm, __shfl_xor(tm, 2));
        tm = fmaxf(tm, __shfl_xor(tm, 4));
        tm = fmaxf(tm, __shfl_xor(tm, 8));
        float mo = m_s[q];
        float mn = fmaxf(mo, tm);
        float rsc = __expf(mo - mn);
        float p0 = __expf(sc0 - mn), p1 = __expf(sc1 - mn);
        float p2 = __expf(sc2 - mn), p3 = __expf(sc3 - mn);
        float ps = (p0+p1)+(p2+p3);
        ps += __shfl_xor(ps, 1); ps += __shfl_xor(ps, 2);
        ps += __shfl_xor(ps, 4); ps += __shfl_xor(ps, 8);
        if (c == 0){ m_s[q] = mn; l_s[q] = l_s[q]*rsc + ps; rs_s[par][q] = rsc; }
        ushort4v pv;
        pv[0] = f2bf(p0); pv[1] = f2bf(p1); pv[2] = f2bf(p2); pv[3] = f2bf(p3);
        *(ushort4v*)&pt[par][q][c*4] = pv;
        __syncthreads();
        // rescale + MFMA (wave: rows rg*16..+15, cols cq*32..+31)
        int rb = rg*16 + ((lane>>4)<<2);
        float rv0 = rs_s[par][rb + 0];
        float rv1 = rs_s[par][rb + 1];
        float rv2 = rs_s[par][rb + 2];
        float rv3 = rs_s[par][rb + 3];
        acc[0][0]*=rv0; acc[0][1]*=rv1; acc[0][2]*=rv2; acc[0][3]*=rv3;
        acc[1][0]*=rv0; acc[1][1]*=rv1; acc[1][2]*=rv2; acc[1][3]*=rv3;
        #pragma unroll
        for (int kk=0;kk<2;kk++){
            short8 af = *(const short8*)&pt[par][rg*16 + l16][kk*32 + khalf];
            short8 b0 = *(const short8*)&vt[par][cq*32 + l16][kk*32 + khalf];
            short8 b1 = *(const short8*)&vt[par][cq*32 + 16 + l16][kk*32 + khalf];
            acc[0] = __builtin_amdgcn_mfma_f32_16x16x32_bf16(af, b0, acc[0], 0, 0, 0);
            acc[1] = __builtin_amdgcn_mfma_f32_16x16x32_bf16(af, b1, acc[1], 0, 0, 0);
        }
    }
    // epilogue: /l, elu, store fp32
    int rb = rg*16 + ((lane>>4)<<2);
    #pragma unroll
    for (int reg=0;reg<4;reg++){
        int r = rb + reg;
        float inv = 1.f / l_s[r];
        #pragma unroll
        for (int nf=0;nf<2;nf++){
            float v = acc[nf][reg] * inv;
            v = v > 0.f ? v : (__expf(v) - 1.f);
            out[((long)(b*Nn + i0 + r))*FOn + cq*32 + nf*16 + l16] = v;
        }
    }
}

extern "C" void kernel_launch(void* const* d_in, const int* in_sizes, int n_in,
                              void* d_out, int out_size, void* d_ws, size_t ws_size,
                              hipStream_t stream){
    const float* h  = (const float*)d_in[0];
    const int* adj  = (const int*)d_in[1];
    const float* W  = (const float*)d_in[2];
    const float* a  = (const float*)d_in[3];
    float* out = (float*)d_out;
    char* ws = (char*)d_ws;
    unsigned short* WT  = (unsigned short*)(ws);                   //    65,536 B (128x256 bf16)
    unsigned short* WhT = (unsigned short*)(ws + 65536);           // 4,194,304 B (8x128x2048 bf16)
    float* s1           = (float*)(ws + 65536 + 4194304);          //    65,536 B
    float* s2           = (float*)(ws + 65536 + 4194304 + 65536);  //    65,536 B

    k0_wt   <<<128, 256, 0, stream>>>(W, WT);
    k1_gemm <<<512, 256, 0, stream>>>(h, WT, a, WhT, s1, s2);
    k3_flash<<<512, 512, 0, stream>>>(adj, WhT, s1, s2, out);
}